// Round 2
// baseline (1741.700 us; speedup 1.0000x reference)
//
#include <hip/hip_runtime.h>
#include <hip/hip_bf16.h>
#include <math.h>

// ---------------------------------------------------------------------------
// SwinTransformerBlock round 2: fp32 compute, bf16 intermediates.
// Workspace capped at 4 x 50.33 MB = 201.3 MB (round-1 crash diagnosed as
// d_ws overflow at 453 MB).
//   buf0 = xt   [N,192] bf16   (token-major input, residual for LN1)
//   buf1 = q -> y (attention writes in-place) -> h_chunk [32768,768]
//   buf2 = k -> x1 (LN1 output, MLP input + residual)
//   buf3 = v -> z (Wo out)  -> m (MLP out)
// Pipeline:
//   k_tin; 3x k_gemm (q,k,v); k_attn (y=q alias); k_gemm (z=wo); k_ln (x1);
//   4x { k_gemm w1+GELU (h_chunk) ; k_gemm w2 (m rows) }; k_ln_out.
// ---------------------------------------------------------------------------

#define DEVI __device__ __forceinline__

static constexpr int CH    = 192;
static constexpr int HH    = 64;
static constexpr int WW    = 64;
static constexpr int NTOK  = 32 * HH * WW;   // 131072
static constexpr int MLPD  = 768;

DEVI float bf2f(unsigned short u) { return __uint_as_float(((unsigned)u) << 16); }
DEVI float ldbf(const __hip_bfloat16* p) { return __bfloat162float(*p); }

// ---------------- transpose in: x[b,c,h,w] -> xt[t,c] bf16 ------------------
__global__ __launch_bounds__(256) void k_tin(const float* __restrict__ x,
                                             __hip_bfloat16* __restrict__ xt) {
    __shared__ float lds[CH * 65];
    int bh = blockIdx.x;              // b*64 + h
    int b = bh >> 6, h = bh & 63;
    const float* xp = x + ((size_t)b * CH) * (HH * WW) + (size_t)h * WW;
    int tid = threadIdx.x;
    int w = tid & 63;
    #pragma unroll
    for (int it = 0; it < CH / 4; ++it) {
        int c = it * 4 + (tid >> 6);
        lds[c * 65 + w] = xp[(size_t)c * (HH * WW) + w];
    }
    __syncthreads();
    __hip_bfloat16* op = xt + (size_t)bh * 64 * CH;
    #pragma unroll
    for (int it = 0; it < 48; ++it) {
        int idx = it * 256 + tid;
        int tok = idx / CH;
        int c = idx - tok * CH;
        op[idx] = __float2bfloat16(lds[c * 65 + tok]);
    }
}

// ---------------- generic tiled GEMM: C = act(A @ B + bias) -----------------
// A: [rows, K] bf16 row-major.  B: [K, NC] fp32 row-major.  C: [rows, NC] bf16.
template<int K, int NC, bool GELU, bool BIAS>
__global__ __launch_bounds__(256) void k_gemm(const __hip_bfloat16* __restrict__ A,
                                              const float* __restrict__ Bm,
                                              const float* __restrict__ bias,
                                              __hip_bfloat16* __restrict__ Cm) {
    __shared__ float As[32][65];   // [k][row]
    __shared__ float Bs[32][68];   // [k][col], stride 68 keeps float4 16B-aligned
    int tid = threadIdx.x;
    int r0 = blockIdx.y * 64;
    int n0 = blockIdx.x * 64;
    int trow = tid >> 4, tcol = tid & 15;
    int arow = tid >> 2;             // 0..63
    int akcol = (tid & 3) * 8;       // 0,8,16,24
    int bk = tid >> 3;               // 0..31
    int bn = (tid & 7) * 8;          // 0..56
    float acc[4][4] = {};

    for (int kt = 0; kt < K / 32; ++kt) {
        // stage A tile (bf16x8 vector load, transpose into As[k][row])
        const __hip_bfloat16* ap = A + (size_t)(r0 + arow) * K + kt * 32 + akcol;
        uint4 pk = *reinterpret_cast<const uint4*>(ap);
        const unsigned short* ps = reinterpret_cast<const unsigned short*>(&pk);
        #pragma unroll
        for (int j = 0; j < 8; ++j) As[akcol + j][arow] = bf2f(ps[j]);
        // stage B tile (float4 x2)
        const float* bp = Bm + (size_t)(kt * 32 + bk) * NC + n0 + bn;
        float4 b0 = *reinterpret_cast<const float4*>(bp);
        float4 b1 = *reinterpret_cast<const float4*>(bp + 4);
        *reinterpret_cast<float4*>(&Bs[bk][bn])     = b0;
        *reinterpret_cast<float4*>(&Bs[bk][bn + 4]) = b1;
        __syncthreads();
        #pragma unroll
        for (int k = 0; k < 32; ++k) {
            float a[4];
            #pragma unroll
            for (int i = 0; i < 4; ++i) a[i] = As[k][trow * 4 + i];
            float4 bb = *reinterpret_cast<const float4*>(&Bs[k][tcol * 4]);
            #pragma unroll
            for (int i = 0; i < 4; ++i) {
                acc[i][0] += a[i] * bb.x;
                acc[i][1] += a[i] * bb.y;
                acc[i][2] += a[i] * bb.z;
                acc[i][3] += a[i] * bb.w;
            }
        }
        __syncthreads();
    }
    #pragma unroll
    for (int i = 0; i < 4; ++i) {
        size_t row = (size_t)r0 + trow * 4 + i;
        #pragma unroll
        for (int j = 0; j < 4; ++j) {
            int col = n0 + tcol * 4 + j;
            float v = acc[i][j];
            if constexpr (BIAS) v += bias[col];
            if constexpr (GELU) v = 0.5f * v * (1.0f + erff(v * 0.70710678118654752f));
            Cm[row * NC + col] = __float2bfloat16(v);
        }
    }
}

// ---------------- windowed attention ----------------------------------------
// window (b, h0, w0): tokens l=(m1,m2) at pixel (m1*16+h0, m2*16+w0).
// scores scaled by C^-0.5 (per reference NOTE), softmax over j, y = a @ v.
// NOTE: Y may alias Q (each thread reads its own q row into registers before
// writing y to the same addresses; windows are block-disjoint) -> no __restrict__.
__global__ __launch_bounds__(128) void k_attn(const __hip_bfloat16* Q,
                                              const __hip_bfloat16* __restrict__ Kb,
                                              const __hip_bfloat16* __restrict__ Vb,
                                              __hip_bfloat16* Y) {
    __shared__ float kls[16 * 198];  // [tok][head*33 + d] (33-stride kills bank aliasing)
    __shared__ float vls[16 * 198];
    int win = blockIdx.x;
    int b = win >> 8;
    int rem = win & 255;
    int h0 = rem >> 4, w0 = rem & 15;
    int tid = threadIdx.x;

    for (int idx = tid; idx < 16 * CH; idx += 128) {
        int tok = idx / CH;
        int c = idx - tok * CH;
        int n = c >> 5, d = c & 31;
        int m1 = tok >> 2, m2 = tok & 3;
        size_t t = ((size_t)(b * 64 + m1 * 16 + h0)) * 64 + m2 * 16 + w0;
        kls[tok * 198 + n * 33 + d] = ldbf(Kb + t * CH + c);
        vls[tok * 198 + n * 33 + d] = ldbf(Vb + t * CH + c);
    }
    __syncthreads();

    if (tid < 96) {
        int n = tid >> 4, i = tid & 15;
        int m1 = i >> 2, m2 = i & 3;
        size_t t = ((size_t)(b * 64 + m1 * 16 + h0)) * 64 + m2 * 16 + w0;
        const float scale = 0.07216878364870322f;  // 192^-0.5
        const __hip_bfloat16* qp = Q + t * CH + n * 32;
        float qr[32];
        #pragma unroll
        for (int d = 0; d < 32; ++d) qr[d] = ldbf(qp + d) * scale;
        float sc[16];
        float mx = -1e30f;
        #pragma unroll
        for (int j = 0; j < 16; ++j) {
            const float* kp = &kls[j * 198 + n * 33];
            float s = 0.f;
            #pragma unroll
            for (int d = 0; d < 32; ++d) s += qr[d] * kp[d];
            sc[j] = s;
            mx = fmaxf(mx, s);
        }
        float sum = 0.f;
        #pragma unroll
        for (int j = 0; j < 16; ++j) { sc[j] = expf(sc[j] - mx); sum += sc[j]; }
        float inv = 1.0f / sum;
        float accv[32];
        #pragma unroll
        for (int d = 0; d < 32; ++d) accv[d] = 0.f;
        #pragma unroll
        for (int j = 0; j < 16; ++j) {
            float a = sc[j] * inv;
            const float* vp = &vls[j * 198 + n * 33];
            #pragma unroll
            for (int d = 0; d < 32; ++d) accv[d] += a * vp[d];
        }
        __hip_bfloat16* yp = Y + t * CH + n * 32;
        #pragma unroll
        for (int d = 0; d < 32; ++d) yp[d] = __float2bfloat16(accv[d]);
    }
}

// ---------------- LayerNorm (token-major out) -------------------------------
__global__ __launch_bounds__(256) void k_ln(const __hip_bfloat16* __restrict__ Zin,
                                            const __hip_bfloat16* __restrict__ Res,
                                            const float* __restrict__ g,
                                            const float* __restrict__ be,
                                            __hip_bfloat16* __restrict__ Out) {
    int tid = threadIdx.x;
    int wv = tid >> 6, lane = tid & 63;
    size_t t = (size_t)blockIdx.x * 4 + wv;
    const __hip_bfloat16* zp = Zin + t * CH;
    const __hip_bfloat16* rp = Res + t * CH;
    int c0 = lane * 3;
    float v[3];
    #pragma unroll
    for (int j = 0; j < 3; ++j) v[j] = ldbf(zp + c0 + j) + ldbf(rp + c0 + j);
    float s = v[0] + v[1] + v[2];
    #pragma unroll
    for (int m = 1; m < 64; m <<= 1) s += __shfl_xor(s, m);
    float mean = s * (1.0f / 192.0f);
    float cv[3], ss = 0.f;
    #pragma unroll
    for (int j = 0; j < 3; ++j) { cv[j] = v[j] - mean; ss += cv[j] * cv[j]; }
    #pragma unroll
    for (int m = 1; m < 64; m <<= 1) ss += __shfl_xor(ss, m);
    float rs = rsqrtf(ss * (1.0f / 192.0f) + 1e-5f);
    __hip_bfloat16* op = Out + t * CH;
    #pragma unroll
    for (int j = 0; j < 3; ++j)
        op[c0 + j] = __float2bfloat16(cv[j] * rs * g[c0 + j] + be[c0 + j]);
}

// ---------------- final LN + transpose out ----------------------------------
__global__ __launch_bounds__(256) void k_ln_out(const __hip_bfloat16* __restrict__ Min,
                                                const __hip_bfloat16* __restrict__ Res,
                                                const float* __restrict__ g,
                                                const float* __restrict__ be,
                                                float* __restrict__ out) {
    __shared__ float lds[CH * 65];
    int bh = blockIdx.x;
    int b = bh >> 6, h = bh & 63;
    int tid = threadIdx.x;
    int wv = tid >> 6, lane = tid & 63;
    int c0 = lane * 3;
    float gv[3], bv[3];
    #pragma unroll
    for (int j = 0; j < 3; ++j) { gv[j] = g[c0 + j]; bv[j] = be[c0 + j]; }
    for (int it = 0; it < 16; ++it) {
        int tok = it * 4 + wv;
        size_t t = (size_t)bh * 64 + tok;
        const __hip_bfloat16* mp = Min + t * CH;
        const __hip_bfloat16* rp = Res + t * CH;
        float v[3];
        #pragma unroll
        for (int j = 0; j < 3; ++j) v[j] = ldbf(mp + c0 + j) + ldbf(rp + c0 + j);
        float s = v[0] + v[1] + v[2];
        #pragma unroll
        for (int m = 1; m < 64; m <<= 1) s += __shfl_xor(s, m);
        float mean = s * (1.0f / 192.0f);
        float cv[3], ss = 0.f;
        #pragma unroll
        for (int j = 0; j < 3; ++j) { cv[j] = v[j] - mean; ss += cv[j] * cv[j]; }
        #pragma unroll
        for (int m = 1; m < 64; m <<= 1) ss += __shfl_xor(ss, m);
        float rs = rsqrtf(ss * (1.0f / 192.0f) + 1e-5f);
        #pragma unroll
        for (int j = 0; j < 3; ++j)
            lds[(c0 + j) * 65 + tok] = cv[j] * rs * gv[j] + bv[j];
    }
    __syncthreads();
    float* op = out + (size_t)b * CH * (HH * WW) + (size_t)h * WW;
    #pragma unroll
    for (int it = 0; it < 48; ++it) {
        int idx = it * 256 + tid;
        int c = idx >> 6;
        int w = idx & 63;
        op[(size_t)c * (HH * WW) + w] = lds[c * 65 + w];
    }
}

// ---------------------------------------------------------------------------
extern "C" void kernel_launch(void* const* d_in, const int* in_sizes, int n_in,
                              void* d_out, int out_size, void* d_ws, size_t ws_size,
                              hipStream_t stream) {
    const float* x   = (const float*)d_in[0];
    const float* wq  = (const float*)d_in[1];
    const float* wk  = (const float*)d_in[2];
    const float* wv  = (const float*)d_in[3];
    const float* wo  = (const float*)d_in[4];
    const float* w1  = (const float*)d_in[5];
    const float* b1  = (const float*)d_in[6];
    const float* w2  = (const float*)d_in[7];
    const float* b2  = (const float*)d_in[8];
    const float* g1  = (const float*)d_in[9];
    const float* be1 = (const float*)d_in[10];
    const float* g2  = (const float*)d_in[11];
    const float* be2 = (const float*)d_in[12];
    float* out = (float*)d_out;

    char* ws = (char*)d_ws;
    const size_t SZ = (size_t)NTOK * CH * sizeof(__hip_bfloat16);  // 50,331,648 B
    __hip_bfloat16* xt = (__hip_bfloat16*)(ws);           // buf0
    __hip_bfloat16* qb = (__hip_bfloat16*)(ws + SZ);      // buf1: q -> y -> h_chunk
    __hip_bfloat16* kb = (__hip_bfloat16*)(ws + 2 * SZ);  // buf2: k -> x1
    __hip_bfloat16* vb = (__hip_bfloat16*)(ws + 3 * SZ);  // buf3: v -> z -> m
    __hip_bfloat16* yb = qb;   // attention output aliases q (safe, see k_attn)
    __hip_bfloat16* zb = vb;   // wo output overwrites v (v dead after attn)
    __hip_bfloat16* x1 = kb;   // LN1 output overwrites k
    __hip_bfloat16* hb = qb;   // MLP hidden chunk [32768,768] == 50.33 MB exactly
    __hip_bfloat16* mb = vb;   // MLP output overwrites z (z dead after LN1)

    dim3 g192(3, NTOK / 64);

    k_tin<<<2048, 256, 0, stream>>>(x, xt);
    k_gemm<192, 192, false, false><<<g192, 256, 0, stream>>>(xt, wq, nullptr, qb);
    k_gemm<192, 192, false, false><<<g192, 256, 0, stream>>>(xt, wk, nullptr, kb);
    k_gemm<192, 192, false, false><<<g192, 256, 0, stream>>>(xt, wv, nullptr, vb);
    k_attn<<<8192, 128, 0, stream>>>(qb, kb, vb, yb);
    k_gemm<192, 192, false, false><<<g192, 256, 0, stream>>>(yb, wo, nullptr, zb);
    k_ln<<<NTOK / 4, 256, 0, stream>>>(zb, xt, g1, be1, x1);

    // MLP in 4 row-chunks of 32768 so the hidden tensor never exceeds 50.33 MB
    const int CHUNK = NTOK / 4;
    dim3 gh(12, CHUNK / 64), gm(3, CHUNK / 64);
    for (int c = 0; c < 4; ++c) {
        const __hip_bfloat16* x1c = x1 + (size_t)c * CHUNK * CH;
        __hip_bfloat16* mc = mb + (size_t)c * CHUNK * CH;
        k_gemm<192, MLPD, true,  true ><<<gh, 256, 0, stream>>>(x1c, w1, b1, hb);
        k_gemm<MLPD, 192, false, true ><<<gm, 256, 0, stream>>>(hb, w2, b2, mc);
    }
    k_ln_out<<<2048, 256, 0, stream>>>(mb, x1, g2, be2, out);
}

// Round 4
// 578.462 us; speedup vs baseline: 3.0109x; 3.0109x over previous
//
#include <hip/hip_runtime.h>
#include <hip/hip_bf16.h>
#include <math.h>

// ---------------------------------------------------------------------------
// Round 4: bf16 MFMA GEMMs + window-contiguous token layout. (r3 + compile fix)
//   k_wprep x6: weights fp32 [K][N] -> bf16 transposed [N][K]
//   k_tin:      x[B,C,H,W] -> xt[u,192] bf16, u = window-major token order
//   k_mgemm x3: q/k/v = xt @ W            (MFMA 16x16x32 bf16, 128x64 tiles)
//   k_attn:     windowed attention on contiguous 16-token windows (y = q alias)
//   k_mgemm:    z = y @ wo
//   k_ln:       x1 = LN(z + xt)
//   4x { k_mgemm w1+GELU ; k_mgemm w2 }   (MLP chunked: h <= 50.3 MB)
//   k_ln_out:   out = transpose(LN(m + x1))
// Workspace: 4 x 50.33 MB bufs + 0.9 MB bf16 weights = 202.2 MB.
// u-order: u = (b<<12)|(h0<<8)|(w0<<4)|(m1<<2)|m2, pixel h=m1*16+h0, w=m2*16+w0.
// ---------------------------------------------------------------------------

#define DEVI __device__ __forceinline__

static constexpr int CH   = 192;
static constexpr int NTOK = 32 * 64 * 64;   // 131072
static constexpr int MLPD = 768;

typedef short bf16x8 __attribute__((ext_vector_type(8)));
typedef float f32x4  __attribute__((ext_vector_type(4)));

DEVI float bf2f(unsigned short u) { return __uint_as_float(((unsigned)u) << 16); }
DEVI unsigned short f2bf(float f) {
    __hip_bfloat16 h = __float2bfloat16(f);
    return *reinterpret_cast<unsigned short*>(&h);
}

DEVI void gload_lds16(const void* g, void* l) {
    __builtin_amdgcn_global_load_lds(
        (const __attribute__((address_space(1))) void*)g,
        (__attribute__((address_space(3))) void*)l, 16, 0, 0);
}

// ---------------- weight prep: W[K][N] fp32 -> Wt[N][K] bf16 ----------------
__global__ __launch_bounds__(256) void k_wprep(const float* __restrict__ W,
                                               __hip_bfloat16* __restrict__ Wt,
                                               int K, int N) {
    int idx = blockIdx.x * 256 + threadIdx.x;
    if (idx >= K * N) return;
    int n = idx / K, k = idx - n * K;
    Wt[idx] = __float2bfloat16(W[(size_t)k * N + n]);
}

// ---------------- transpose in: x[b,c,h,w] -> xt[u,c] bf16 ------------------
__global__ __launch_bounds__(256) void k_tin(const float* __restrict__ x,
                                             __hip_bfloat16* __restrict__ xt) {
    __shared__ float lds[CH * 65];
    int bh = blockIdx.x;              // b*64 + h
    int b = bh >> 6, h = bh & 63;
    const float* xp = x + ((size_t)b * CH) * 4096 + (size_t)h * 64;
    int tid = threadIdx.x;
    int w = tid & 63;
    #pragma unroll
    for (int it = 0; it < CH / 4; ++it) {
        int c = it * 4 + (tid >> 6);
        lds[c * 65 + w] = xp[(size_t)c * 4096 + w];
    }
    __syncthreads();
    int m1 = h >> 4, h0 = h & 15;
    int ubase = (b << 12) | (h0 << 8) | (m1 << 2);
    #pragma unroll
    for (int it = 0; it < 48; ++it) {
        int idx = it * 256 + tid;
        int tok = idx / CH;
        int c = idx - tok * CH;
        int u = ubase | ((tok & 15) << 4) | (tok >> 4);
        xt[(size_t)u * CH + c] = __float2bfloat16(lds[c * 65 + tok]);
    }
}

// ---------------- MFMA GEMM: C[rows,NC] = act(A[rows,K] @ Bt[NC,K]^T + bias) -
// 128x64 tile, BK=64, 4 waves (2x2), wave tile 64x32 (4x2 16x16 frags).
// LDS tiles XOR-swizzled (byte ^= (row&7)<<4) via pre-swizzled global source.
template<int K, bool GELU, bool BIAS>
__global__ __launch_bounds__(256) void k_mgemm(const __hip_bfloat16* __restrict__ A,
                                               const __hip_bfloat16* __restrict__ Bt,
                                               const float* __restrict__ bias,
                                               __hip_bfloat16* __restrict__ Cm,
                                               const int NC) {
    __shared__ __align__(16) char smem[24576];   // As 16KB [128][64], Bs 8KB [64][64]
    char* As = smem;
    char* Bs = smem + 16384;
    const int tid = threadIdx.x;
    const int l  = tid & 63;
    const int w  = tid >> 6;
    const int wr = w >> 1, wc = w & 1;
    const int r0 = blockIdx.y * 128;
    const int n0 = blockIdx.x * 64;

    f32x4 acc[4][2] = {};

    for (int kt = 0; kt < K / 64; ++kt) {
        #pragma unroll
        for (int it = 0; it < 4; ++it) {        // A: 16 x 1KB chunks
            int c = it * 4 + w;
            int s = c * 64 + l;
            int row = s >> 3;
            int ebyte = ((s & 7) << 4) ^ ((row & 7) << 4);
            const __hip_bfloat16* gp = A + (size_t)(r0 + row) * K + kt * 64 + (ebyte >> 1);
            gload_lds16(gp, As + c * 1024);
        }
        #pragma unroll
        for (int it = 0; it < 2; ++it) {        // B: 8 x 1KB chunks
            int c = it * 4 + w;
            int s = c * 64 + l;
            int row = s >> 3;
            int ebyte = ((s & 7) << 4) ^ ((row & 7) << 4);
            const __hip_bfloat16* gp = Bt + (size_t)(n0 + row) * K + kt * 64 + (ebyte >> 1);
            gload_lds16(gp, Bs + c * 1024);
        }
        __syncthreads();
        #pragma unroll
        for (int ks = 0; ks < 2; ++ks) {
            int kb = ks * 64 + ((l >> 4) << 4);  // byte offset of this lane's 8 k-elems
            bf16x8 af[4], bfr[2];
            #pragma unroll
            for (int m = 0; m < 4; ++m) {
                int row = wr * 64 + m * 16 + (l & 15);
                af[m] = *(const bf16x8*)(As + row * 128 + (kb ^ ((row & 7) << 4)));
            }
            #pragma unroll
            for (int n = 0; n < 2; ++n) {
                int row = wc * 32 + n * 16 + (l & 15);
                bfr[n] = *(const bf16x8*)(Bs + row * 128 + (kb ^ ((row & 7) << 4)));
            }
            #pragma unroll
            for (int m = 0; m < 4; ++m)
                #pragma unroll
                for (int n = 0; n < 2; ++n)
                    acc[m][n] = __builtin_amdgcn_mfma_f32_16x16x32_bf16(
                        af[m], bfr[n], acc[m][n], 0, 0, 0);
        }
        __syncthreads();
    }

    const int rl = (l >> 4) * 4;
    const int cl = l & 15;
    #pragma unroll
    for (int n = 0; n < 2; ++n) {
        int col = n0 + wc * 32 + n * 16 + cl;
        float bv = 0.f;
        if constexpr (BIAS) bv = bias[col];
        #pragma unroll
        for (int m = 0; m < 4; ++m) {
            #pragma unroll
            for (int j = 0; j < 4; ++j) {
                size_t row = (size_t)r0 + wr * 64 + m * 16 + rl + j;
                float v = acc[m][n][j] + bv;
                if constexpr (GELU) v = 0.5f * v * (1.0f + erff(v * 0.70710678118654752f));
                Cm[row * NC + col] = __float2bfloat16(v);
            }
        }
    }
}

// ---------------- windowed attention (contiguous windows) -------------------
// Q/K/V/Y in u-order: window win owns rows [win*16, win*16+16). Y aliases Q
// (each thread reads its own q-slice into regs before writing the same slice).
__global__ __launch_bounds__(128) void k_attn(const __hip_bfloat16* Q,
                                              const __hip_bfloat16* __restrict__ Kb,
                                              const __hip_bfloat16* __restrict__ Vb,
                                              __hip_bfloat16* Y) {
    __shared__ __align__(16) unsigned short kls[16 * 200];
    __shared__ __align__(16) unsigned short vls[16 * 200];
    int win = blockIdx.x;
    int tid = threadIdx.x;
    const size_t base = (size_t)win * 16 * CH;

    #pragma unroll
    for (int it = 0; it < 3; ++it) {            // 384 uint4 per tensor
        int idx = it * 128 + tid;
        int row = idx / 24, seg = idx - row * 24;
        uint4 kv = *reinterpret_cast<const uint4*>(Kb + base + row * CH + seg * 8);
        uint4 vv = *reinterpret_cast<const uint4*>(Vb + base + row * CH + seg * 8);
        *reinterpret_cast<uint4*>(&kls[row * 200 + seg * 8]) = kv;
        *reinterpret_cast<uint4*>(&vls[row * 200 + seg * 8]) = vv;
    }
    __syncthreads();

    if (tid < 96) {
        int n = tid >> 4, i = tid & 15;
        const float scale = 0.07216878364870322f;  // 192^-0.5
        const __hip_bfloat16* qp = Q + base + i * CH + n * 32;
        float qr[32];
        #pragma unroll
        for (int sg = 0; sg < 4; ++sg) {
            bf16x8 qv = *reinterpret_cast<const bf16x8*>(qp + sg * 8);
            #pragma unroll
            for (int j = 0; j < 8; ++j) qr[sg * 8 + j] = bf2f((unsigned short)qv[j]) * scale;
        }
        float sc[16];
        float mx = -1e30f;
        #pragma unroll
        for (int j = 0; j < 16; ++j) {
            float s = 0.f;
            #pragma unroll
            for (int sg = 0; sg < 4; ++sg) {
                bf16x8 kk = *reinterpret_cast<const bf16x8*>(&kls[j * 200 + n * 32 + sg * 8]);
                #pragma unroll
                for (int d = 0; d < 8; ++d) s += qr[sg * 8 + d] * bf2f((unsigned short)kk[d]);
            }
            sc[j] = s;
            mx = fmaxf(mx, s);
        }
        float sum = 0.f;
        #pragma unroll
        for (int j = 0; j < 16; ++j) { sc[j] = __expf(sc[j] - mx); sum += sc[j]; }
        float inv = 1.0f / sum;
        float accv[32];
        #pragma unroll
        for (int d = 0; d < 32; ++d) accv[d] = 0.f;
        #pragma unroll
        for (int j = 0; j < 16; ++j) {
            float a = sc[j] * inv;
            #pragma unroll
            for (int sg = 0; sg < 4; ++sg) {
                bf16x8 vv = *reinterpret_cast<const bf16x8*>(&vls[j * 200 + n * 32 + sg * 8]);
                #pragma unroll
                for (int d = 0; d < 8; ++d) accv[sg * 8 + d] += a * bf2f((unsigned short)vv[d]);
            }
        }
        __hip_bfloat16* yp = Y + base + i * CH + n * 32;
        #pragma unroll
        for (int sg = 0; sg < 4; ++sg) {
            union { uint4 u4; unsigned short us[8]; } pk;
            #pragma unroll
            for (int j = 0; j < 8; ++j) pk.us[j] = f2bf(accv[sg * 8 + j]);
            *reinterpret_cast<uint4*>(yp + sg * 8) = pk.u4;
        }
    }
}

// ---------------- LayerNorm (row-order preserved) ---------------------------
__global__ __launch_bounds__(256) void k_ln(const __hip_bfloat16* __restrict__ Zin,
                                            const __hip_bfloat16* __restrict__ Res,
                                            const float* __restrict__ g,
                                            const float* __restrict__ be,
                                            __hip_bfloat16* __restrict__ Out) {
    int tid = threadIdx.x;
    int wv = tid >> 6, lane = tid & 63;
    size_t t = (size_t)blockIdx.x * 4 + wv;
    int c0 = lane * 4;
    bool act = lane < 48;
    float v[4] = {0.f, 0.f, 0.f, 0.f};
    if (act) {
        uint2 za = *reinterpret_cast<const uint2*>(Zin + t * CH + c0);
        uint2 ra = *reinterpret_cast<const uint2*>(Res + t * CH + c0);
        const unsigned short* zs = reinterpret_cast<const unsigned short*>(&za);
        const unsigned short* rs = reinterpret_cast<const unsigned short*>(&ra);
        #pragma unroll
        for (int j = 0; j < 4; ++j) v[j] = bf2f(zs[j]) + bf2f(rs[j]);
    }
    float s = v[0] + v[1] + v[2] + v[3];
    #pragma unroll
    for (int m = 1; m < 64; m <<= 1) s += __shfl_xor(s, m);
    float mean = s * (1.0f / 192.0f);
    float cv[4], ss = 0.f;
    #pragma unroll
    for (int j = 0; j < 4; ++j) { cv[j] = act ? (v[j] - mean) : 0.f; ss += cv[j] * cv[j]; }
    #pragma unroll
    for (int m = 1; m < 64; m <<= 1) ss += __shfl_xor(ss, m);
    float rcp = rsqrtf(ss * (1.0f / 192.0f) + 1e-5f);
    if (act) {
        union { uint2 u2; unsigned short us[4]; } pk;
        #pragma unroll
        for (int j = 0; j < 4; ++j)
            pk.us[j] = f2bf(cv[j] * rcp * g[c0 + j] + be[c0 + j]);
        *reinterpret_cast<uint2*>(Out + t * CH + c0) = pk.u2;
    }
}

// ---------------- final LN + transpose out (u-order in) ---------------------
__global__ __launch_bounds__(256) void k_ln_out(const __hip_bfloat16* __restrict__ Min,
                                                const __hip_bfloat16* __restrict__ Res,
                                                const float* __restrict__ g,
                                                const float* __restrict__ be,
                                                float* __restrict__ out) {
    __shared__ float lds[CH * 65];
    int bh = blockIdx.x;
    int b = bh >> 6, h = bh & 63;
    int tid = threadIdx.x;
    int wv = tid >> 6, lane = tid & 63;
    int c0 = lane * 4;
    bool act = lane < 48;
    int m1 = h >> 4, h0 = h & 15;
    int ubase = (b << 12) | (h0 << 8) | (m1 << 2);
    float gv[4], bv[4];
    #pragma unroll
    for (int j = 0; j < 4; ++j) { gv[j] = act ? g[c0 + j] : 0.f; bv[j] = act ? be[c0 + j] : 0.f; }
    for (int it = 0; it < 16; ++it) {
        int tok = it * 4 + wv;
        int u = ubase | ((tok & 15) << 4) | (tok >> 4);
        float v[4] = {0.f, 0.f, 0.f, 0.f};
        if (act) {
            uint2 ma = *reinterpret_cast<const uint2*>(Min + (size_t)u * CH + c0);
            uint2 ra = *reinterpret_cast<const uint2*>(Res + (size_t)u * CH + c0);
            const unsigned short* ms = reinterpret_cast<const unsigned short*>(&ma);
            const unsigned short* rs = reinterpret_cast<const unsigned short*>(&ra);
            #pragma unroll
            for (int j = 0; j < 4; ++j) v[j] = bf2f(ms[j]) + bf2f(rs[j]);
        }
        float s = v[0] + v[1] + v[2] + v[3];
        #pragma unroll
        for (int m = 1; m < 64; m <<= 1) s += __shfl_xor(s, m);
        float mean = s * (1.0f / 192.0f);
        float cv[4], ss = 0.f;
        #pragma unroll
        for (int j = 0; j < 4; ++j) { cv[j] = act ? (v[j] - mean) : 0.f; ss += cv[j] * cv[j]; }
        #pragma unroll
        for (int m = 1; m < 64; m <<= 1) ss += __shfl_xor(ss, m);
        float rcp = rsqrtf(ss * (1.0f / 192.0f) + 1e-5f);
        if (act) {
            #pragma unroll
            for (int j = 0; j < 4; ++j)
                lds[(c0 + j) * 65 + tok] = cv[j] * rcp * gv[j] + bv[j];
        }
    }
    __syncthreads();
    float* op = out + (size_t)b * CH * 4096 + (size_t)h * 64;
    #pragma unroll
    for (int it = 0; it < 48; ++it) {
        int idx = it * 256 + tid;
        int c = idx >> 6;
        int w = idx & 63;
        op[(size_t)c * 4096 + w] = lds[c * 65 + w];
    }
}

// ---------------------------------------------------------------------------
extern "C" void kernel_launch(void* const* d_in, const int* in_sizes, int n_in,
                              void* d_out, int out_size, void* d_ws, size_t ws_size,
                              hipStream_t stream) {
    const float* x   = (const float*)d_in[0];
    const float* wq  = (const float*)d_in[1];
    const float* wk  = (const float*)d_in[2];
    const float* wv  = (const float*)d_in[3];
    const float* wo  = (const float*)d_in[4];
    const float* w1  = (const float*)d_in[5];
    const float* b1  = (const float*)d_in[6];
    const float* w2  = (const float*)d_in[7];
    const float* b2  = (const float*)d_in[8];
    const float* g1  = (const float*)d_in[9];
    const float* be1 = (const float*)d_in[10];
    const float* g2  = (const float*)d_in[11];
    const float* be2 = (const float*)d_in[12];
    float* out = (float*)d_out;

    char* ws = (char*)d_ws;
    const size_t SZ = (size_t)NTOK * CH * sizeof(__hip_bfloat16);  // 50,331,648 B
    __hip_bfloat16* xt = (__hip_bfloat16*)(ws);           // buf0
    __hip_bfloat16* qb = (__hip_bfloat16*)(ws + SZ);      // buf1: q -> y -> h_chunk
    __hip_bfloat16* kb = (__hip_bfloat16*)(ws + 2 * SZ);  // buf2: k -> x1
    __hip_bfloat16* vb = (__hip_bfloat16*)(ws + 3 * SZ);  // buf3: v -> z -> m
    __hip_bfloat16* yb = qb;
    __hip_bfloat16* zb = vb;
    __hip_bfloat16* x1 = kb;
    __hip_bfloat16* hb = qb;   // MLP hidden chunk [32768,768] = 50.33 MB
    __hip_bfloat16* mb = vb;

    // bf16 transposed weights after the 4 big buffers (+0.9 MB)
    __hip_bfloat16* wqt = (__hip_bfloat16*)(ws + 4 * SZ);
    __hip_bfloat16* wkt = wqt + 192 * 192;
    __hip_bfloat16* wvt = wkt + 192 * 192;
    __hip_bfloat16* wot = wvt + 192 * 192;
    __hip_bfloat16* w1t = wot + 192 * 192;   // [768][192]
    __hip_bfloat16* w2t = w1t + 192 * 768;   // [192][768]

    k_wprep<<<144, 256, 0, stream>>>(wq, wqt, 192, 192);
    k_wprep<<<144, 256, 0, stream>>>(wk, wkt, 192, 192);
    k_wprep<<<144, 256, 0, stream>>>(wv, wvt, 192, 192);
    k_wprep<<<144, 256, 0, stream>>>(wo, wot, 192, 192);
    k_wprep<<<576, 256, 0, stream>>>(w1, w1t, 192, 768);
    k_wprep<<<576, 256, 0, stream>>>(w2, w2t, 768, 192);

    k_tin<<<2048, 256, 0, stream>>>(x, xt);

    dim3 g192(3, NTOK / 128);
    k_mgemm<192, false, false><<<g192, 256, 0, stream>>>(xt, wqt, nullptr, qb, 192);
    k_mgemm<192, false, false><<<g192, 256, 0, stream>>>(xt, wkt, nullptr, kb, 192);
    k_mgemm<192, false, false><<<g192, 256, 0, stream>>>(xt, wvt, nullptr, vb, 192);
    k_attn<<<8192, 128, 0, stream>>>(qb, kb, vb, yb);
    k_mgemm<192, false, false><<<g192, 256, 0, stream>>>(yb, wot, nullptr, zb, 192);
    k_ln<<<NTOK / 4, 256, 0, stream>>>(zb, xt, g1, be1, x1);

    const int CHUNK = NTOK / 4;   // 32768 rows
    dim3 gh(12, CHUNK / 128), gm(3, CHUNK / 128);
    for (int c = 0; c < 4; ++c) {
        const __hip_bfloat16* x1c = x1 + (size_t)c * CHUNK * CH;
        __hip_bfloat16* mc = mb + (size_t)c * CHUNK * CH;
        k_mgemm<192, true,  true ><<<gh, 256, 0, stream>>>(x1c, w1t, b1, hb, MLPD);
        k_mgemm<MLPD, false, true ><<<gm, 256, 0, stream>>>(hb, w2t, b2, mc, 192);
    }
    k_ln_out<<<2048, 256, 0, stream>>>(mb, x1, g2, be2, out);
}

// Round 6
// 512.642 us; speedup vs baseline: 3.3975x; 1.1284x over previous
//
#include <hip/hip_runtime.h>
#include <hip/hip_bf16.h>
#include <math.h>

// ---------------------------------------------------------------------------
// Round 6: r5 + NaN fix in k_attn2 (V-transpose LDS pad slots zeroed; 64B rows).
//   k_wprep x6:  weights fp32 [K][N] -> bf16 transposed [N][K] (wq|wk|wv fused)
//   k_tin:       x[B,C,H,W] -> xt[u,192] bf16 (u = window-major token order)
//   k_mgemm:     qkv[u,576] = xt @ [wq|wk|wv]
//   k_attn2:     MFMA window attention; y overwrites v-slots of qkv
//   k_wogemm:    x1 = LN(y @ wo + xt) * g1 + b1   (in-place over xt)
//   2x { k_mgemm w1+GELU (h) ; k_mgemm w2 (m) }   (MLP, 65536-row chunks)
//   k_ln_out:    out = transpose(LN(m + x1))
// ---------------------------------------------------------------------------

#define DEVI __device__ __forceinline__

static constexpr int CH   = 192;
static constexpr int NTOK = 32 * 64 * 64;   // 131072
static constexpr int MLPD = 768;

typedef short bf16x8 __attribute__((ext_vector_type(8)));
typedef float f32x4  __attribute__((ext_vector_type(4)));

DEVI float bf2f(unsigned short u) { return __uint_as_float(((unsigned)u) << 16); }
DEVI unsigned short f2bf(float f) {
    __hip_bfloat16 h = __float2bfloat16(f);
    return *reinterpret_cast<unsigned short*>(&h);
}

DEVI void gload_lds16(const void* g, void* l) {
    __builtin_amdgcn_global_load_lds(
        (const __attribute__((address_space(1))) void*)g,
        (__attribute__((address_space(3))) void*)l, 16, 0, 0);
}

// ---------------- weight prep: W[K][N] fp32 -> Wt[N][K] bf16 ----------------
__global__ __launch_bounds__(256) void k_wprep(const float* __restrict__ W,
                                               __hip_bfloat16* __restrict__ Wt,
                                               int K, int N) {
    int idx = blockIdx.x * 256 + threadIdx.x;
    if (idx >= K * N) return;
    int n = idx / K, k = idx - n * K;
    Wt[idx] = __float2bfloat16(W[(size_t)k * N + n]);
}

// ---------------- transpose in: x[b,c,h,w] -> xt[u,c] bf16 ------------------
__global__ __launch_bounds__(256) void k_tin(const float* __restrict__ x,
                                             __hip_bfloat16* __restrict__ xt) {
    __shared__ float lds[CH * 65];
    int bh = blockIdx.x;              // b*64 + h
    int b = bh >> 6, h = bh & 63;
    const float* xp = x + ((size_t)b * CH) * 4096 + (size_t)h * 64;
    int tid = threadIdx.x;
    int w = tid & 63;
    #pragma unroll
    for (int it = 0; it < CH / 4; ++it) {
        int c = it * 4 + (tid >> 6);
        lds[c * 65 + w] = xp[(size_t)c * 4096 + w];
    }
    __syncthreads();
    int m1 = h >> 4, h0 = h & 15;
    int ubase = (b << 12) | (h0 << 8) | (m1 << 2);
    #pragma unroll
    for (int it = 0; it < 48; ++it) {
        int idx = it * 256 + tid;
        int tok = idx / CH;
        int c = idx - tok * CH;
        int u = ubase | ((tok & 15) << 4) | (tok >> 4);
        xt[(size_t)u * CH + c] = __float2bfloat16(lds[c * 65 + tok]);
    }
}

// ---------------- MFMA GEMM: C[r, n0+0..63] = act(A@Bt^T + bias) ------------
// 128x64 tile, BK=64, 4 waves (2x2), wave tile 64x32. A row stride = LDA.
template<int K, bool GELU, bool BIAS>
__global__ __launch_bounds__(256) void k_mgemm(const __hip_bfloat16* __restrict__ A,
                                               const __hip_bfloat16* __restrict__ Bt,
                                               const float* __restrict__ bias,
                                               __hip_bfloat16* __restrict__ Cm,
                                               const int LDA, const int LDC) {
    __shared__ __align__(16) char smem[24576];   // As 16KB [128][64], Bs 8KB [64][64]
    char* As = smem;
    char* Bs = smem + 16384;
    const int tid = threadIdx.x;
    const int l  = tid & 63;
    const int w  = tid >> 6;
    const int wr = w >> 1, wc = w & 1;
    const int r0 = blockIdx.y * 128;
    const int n0 = blockIdx.x * 64;

    f32x4 acc[4][2] = {};

    for (int kt = 0; kt < K / 64; ++kt) {
        #pragma unroll
        for (int it = 0; it < 4; ++it) {        // A: 16 x 1KB chunks
            int c = it * 4 + w;
            int s = c * 64 + l;
            int row = s >> 3;
            int ebyte = ((s & 7) << 4) ^ ((row & 7) << 4);
            const __hip_bfloat16* gp = A + (size_t)(r0 + row) * LDA + kt * 64 + (ebyte >> 1);
            gload_lds16(gp, As + c * 1024);
        }
        #pragma unroll
        for (int it = 0; it < 2; ++it) {        // B: 8 x 1KB chunks
            int c = it * 4 + w;
            int s = c * 64 + l;
            int row = s >> 3;
            int ebyte = ((s & 7) << 4) ^ ((row & 7) << 4);
            const __hip_bfloat16* gp = Bt + (size_t)(n0 + row) * K + kt * 64 + (ebyte >> 1);
            gload_lds16(gp, Bs + c * 1024);
        }
        __syncthreads();
        #pragma unroll
        for (int ks = 0; ks < 2; ++ks) {
            int kb = ks * 64 + ((l >> 4) << 4);
            bf16x8 af[4], bfr[2];
            #pragma unroll
            for (int m = 0; m < 4; ++m) {
                int row = wr * 64 + m * 16 + (l & 15);
                af[m] = *(const bf16x8*)(As + row * 128 + (kb ^ ((row & 7) << 4)));
            }
            #pragma unroll
            for (int n = 0; n < 2; ++n) {
                int row = wc * 32 + n * 16 + (l & 15);
                bfr[n] = *(const bf16x8*)(Bs + row * 128 + (kb ^ ((row & 7) << 4)));
            }
            #pragma unroll
            for (int m = 0; m < 4; ++m)
                #pragma unroll
                for (int n = 0; n < 2; ++n)
                    acc[m][n] = __builtin_amdgcn_mfma_f32_16x16x32_bf16(
                        af[m], bfr[n], acc[m][n], 0, 0, 0);
        }
        __syncthreads();
    }

    const int rl = (l >> 4) * 4;
    const int cl = l & 15;
    #pragma unroll
    for (int n = 0; n < 2; ++n) {
        int col = n0 + wc * 32 + n * 16 + cl;
        float bv = 0.f;
        if constexpr (BIAS) bv = bias[col];
        #pragma unroll
        for (int m = 0; m < 4; ++m) {
            #pragma unroll
            for (int j = 0; j < 4; ++j) {
                size_t row = (size_t)r0 + wr * 64 + m * 16 + rl + j;
                float v = acc[m][n][j] + bv;
                if constexpr (GELU) v = 0.5f * v * (1.0f + erff(v * 0.70710678118654752f));
                Cm[row * LDC + col] = __float2bfloat16(v);
            }
        }
    }
}

// ---------------- MFMA window attention -------------------------------------
// qkv[u,576]: q 0..191 | k 192..383 | v 384..575. One wave per 16-token window.
// S^T = mfma(A=K, B=Q). Softmax over K-tokens via shfl_xor(16/32).
// PV: A = P (bf16, LDS, K padded 16->32 with zeros), B = vT (LDS, 64B rows,
// token slots 16..31 ZEROED -- 0 x garbage = NaN was the r5 bug).
__global__ __launch_bounds__(256) void k_attn2(__hip_bfloat16* qkv) {
    // per-wave: vT 192 rows x 64B = 12288B, P 16 rows x 80B = 1280B
    __shared__ __align__(16) char lds[4 * 13568];
    const int tid = threadIdx.x;
    const int l = tid & 63;
    const int w = tid >> 6;
    const int win = blockIdx.x * 4 + w;
    char* vt = lds + w * 13568;
    char* pb = vt + 12288;

    // zero vT pad slots (tokens 16..31 of each channel row)
    #pragma unroll
    for (int rr = 0; rr < 3; ++rr) {
        char* zp = vt + (l * 3 + rr) * 64 + 32;
        *(uint4*)zp        = make_uint4(0u, 0u, 0u, 0u);
        *(uint4*)(zp + 16) = make_uint4(0u, 0u, 0u, 0u);
    }
    // zero P pad region (k = 16..31)
    {
        int r = l >> 2, o = (l & 3) * 8;
        *(uint2*)(pb + r * 80 + 32 + o) = make_uint2(0u, 0u);
    }

    const __hip_bfloat16* base = qkv + (size_t)win * 16 * 576;

    // V loads (coalesced uint4) -> regs
    uint4 vr[6];
    #pragma unroll
    for (int it = 0; it < 6; ++it) {
        int flat = it * 64 + l;
        int row = flat / 24, seg = flat - row * 24;
        vr[it] = *(const uint4*)(base + (size_t)row * 576 + 384 + seg * 8);
    }
    // Q,K fragment loads direct from global
    bf16x8 qf[6], kf[6];
    #pragma unroll
    for (int h = 0; h < 6; ++h) {
        const __hip_bfloat16* rp = base + (size_t)(l & 15) * 576;
        int off = h * 32 + (l >> 4) * 8;
        qf[h] = *(const bf16x8*)(rp + off);
        kf[h] = *(const bf16x8*)(rp + 192 + off);
    }
    // scatter V -> vT[ch][token] (64B rows)
    #pragma unroll
    for (int it = 0; it < 6; ++it) {
        int flat = it * 64 + l;
        int row = flat / 24, seg = flat - row * 24;
        const unsigned short* e = (const unsigned short*)&vr[it];
        #pragma unroll
        for (int j = 0; j < 8; ++j)
            *(unsigned short*)(vt + (seg * 8 + j) * 64 + row * 2) = e[j];
    }

    const float scale = 0.07216878364870322f;  // 192^-0.5
    __hip_bfloat16* yp = qkv + (size_t)win * 16 * 576 + 384;

    #pragma unroll
    for (int h = 0; h < 6; ++h) {
        f32x4 s = {};
        s = __builtin_amdgcn_mfma_f32_16x16x32_bf16(kf[h], qf[h], s, 0, 0, 0);
        float sc[4];
        #pragma unroll
        for (int r = 0; r < 4; ++r) sc[r] = s[r] * scale;
        float mx = fmaxf(fmaxf(sc[0], sc[1]), fmaxf(sc[2], sc[3]));
        mx = fmaxf(mx, __shfl_xor(mx, 16));
        mx = fmaxf(mx, __shfl_xor(mx, 32));
        float e0 = __expf(sc[0] - mx), e1 = __expf(sc[1] - mx);
        float e2 = __expf(sc[2] - mx), e3 = __expf(sc[3] - mx);
        float sum = e0 + e1 + e2 + e3;
        sum += __shfl_xor(sum, 16);
        sum += __shfl_xor(sum, 32);
        float inv = 1.0f / sum;
        // pack P[i=l&15][j=(l>>4)*4 + 0..3] as 2 x bf16x2
        unsigned int pa = ((unsigned)f2bf(e1 * inv) << 16) | f2bf(e0 * inv);
        unsigned int pc = ((unsigned)f2bf(e3 * inv) << 16) | f2bf(e2 * inv);
        char* pw = pb + (l & 15) * 80 + (l >> 4) * 8;
        *(unsigned int*)pw = pa;
        *(unsigned int*)(pw + 4) = pc;
        // PV
        bf16x8 pf = *(const bf16x8*)(pb + (l & 15) * 80 + (l >> 4) * 16);
        bf16x8 v0 = *(const bf16x8*)(vt + (h * 32 + (l & 15)) * 64 + (l >> 4) * 16);
        bf16x8 v1 = *(const bf16x8*)(vt + (h * 32 + 16 + (l & 15)) * 64 + (l >> 4) * 16);
        f32x4 y0 = {}, y1 = {};
        y0 = __builtin_amdgcn_mfma_f32_16x16x32_bf16(pf, v0, y0, 0, 0, 0);
        y1 = __builtin_amdgcn_mfma_f32_16x16x32_bf16(pf, v1, y1, 0, 0, 0);
        #pragma unroll
        for (int r = 0; r < 4; ++r) {
            int row = (l >> 4) * 4 + r;
            yp[(size_t)row * 576 + h * 32 + (l & 15)]      = __float2bfloat16(y0[r]);
            yp[(size_t)row * 576 + h * 32 + 16 + (l & 15)] = __float2bfloat16(y1[r]);
        }
    }
}

// ---------------- Wo GEMM with fused residual + LayerNorm -------------------
// Full-row tile 128x192, K=192. 4 waves, wave w owns rows w*32..w*32+31.
__global__ __launch_bounds__(256) void k_wogemm(const __hip_bfloat16* __restrict__ Y,
                                                const __hip_bfloat16* __restrict__ Wt,
                                                const __hip_bfloat16* Res,
                                                const float* __restrict__ g,
                                                const float* __restrict__ be,
                                                __hip_bfloat16* X1) {
    __shared__ __align__(16) char smem[40960];   // As 16KB [128][64], Bs 24KB [192][64]
    char* As = smem;
    char* Bs = smem + 16384;
    const int tid = threadIdx.x;
    const int l = tid & 63;
    const int w = tid >> 6;
    const int r0 = blockIdx.x * 128;

    f32x4 acc[2][12] = {};

    for (int kt = 0; kt < 3; ++kt) {
        #pragma unroll
        for (int it = 0; it < 4; ++it) {        // A: 16 chunks
            int c = it * 4 + w;
            int s = c * 64 + l;
            int row = s >> 3;
            int ebyte = ((s & 7) << 4) ^ ((row & 7) << 4);
            const __hip_bfloat16* gp = Y + (size_t)(r0 + row) * 576 + kt * 64 + (ebyte >> 1);
            gload_lds16(gp, As + c * 1024);
        }
        #pragma unroll
        for (int it = 0; it < 6; ++it) {        // B: 24 chunks (192 rows)
            int c = it * 4 + w;
            int s = c * 64 + l;
            int row = s >> 3;
            int ebyte = ((s & 7) << 4) ^ ((row & 7) << 4);
            const __hip_bfloat16* gp = Wt + (size_t)row * 192 + kt * 64 + (ebyte >> 1);
            gload_lds16(gp, Bs + c * 1024);
        }
        __syncthreads();
        #pragma unroll
        for (int ks = 0; ks < 2; ++ks) {
            int kb = ks * 64 + ((l >> 4) << 4);
            bf16x8 af[2], bfr[12];
            #pragma unroll
            for (int m = 0; m < 2; ++m) {
                int row = w * 32 + m * 16 + (l & 15);
                af[m] = *(const bf16x8*)(As + row * 128 + (kb ^ ((row & 7) << 4)));
            }
            #pragma unroll
            for (int n = 0; n < 12; ++n) {
                int row = n * 16 + (l & 15);
                bfr[n] = *(const bf16x8*)(Bs + row * 128 + (kb ^ ((row & 7) << 4)));
            }
            #pragma unroll
            for (int m = 0; m < 2; ++m)
                #pragma unroll
                for (int n = 0; n < 12; ++n)
                    acc[m][n] = __builtin_amdgcn_mfma_f32_16x16x32_bf16(
                        af[m], bfr[n], acc[m][n], 0, 0, 0);
        }
        __syncthreads();
    }

    // epilogue: residual + per-row LN (wave owns full rows)
    float gv[12], bev[12];
    #pragma unroll
    for (int n = 0; n < 12; ++n) {
        int col = n * 16 + (l & 15);
        gv[n] = g[col];
        bev[n] = be[col];
    }
    #pragma unroll
    for (int m = 0; m < 2; ++m) {
        #pragma unroll
        for (int r = 0; r < 4; ++r) {
            size_t row = (size_t)r0 + w * 32 + m * 16 + (l >> 4) * 4 + r;
            float v[12];
            float sum = 0.f;
            #pragma unroll
            for (int n = 0; n < 12; ++n) {
                int col = n * 16 + (l & 15);
                v[n] = acc[m][n][r] +
                       bf2f(*reinterpret_cast<const unsigned short*>(Res + row * 192 + col));
                sum += v[n];
            }
            sum += __shfl_xor(sum, 1);
            sum += __shfl_xor(sum, 2);
            sum += __shfl_xor(sum, 4);
            sum += __shfl_xor(sum, 8);
            float mean = sum * (1.0f / 192.0f);
            float ss = 0.f;
            #pragma unroll
            for (int n = 0; n < 12; ++n) { v[n] -= mean; ss += v[n] * v[n]; }
            ss += __shfl_xor(ss, 1);
            ss += __shfl_xor(ss, 2);
            ss += __shfl_xor(ss, 4);
            ss += __shfl_xor(ss, 8);
            float rs = rsqrtf(ss * (1.0f / 192.0f) + 1e-5f);
            #pragma unroll
            for (int n = 0; n < 12; ++n) {
                int col = n * 16 + (l & 15);
                *reinterpret_cast<unsigned short*>(X1 + row * 192 + col) =
                    f2bf(v[n] * rs * gv[n] + bev[n]);
            }
        }
    }
}

// ---------------- final LN + transpose out (u-order in) ---------------------
__global__ __launch_bounds__(256) void k_ln_out(const __hip_bfloat16* __restrict__ Min,
                                                const __hip_bfloat16* __restrict__ Res,
                                                const float* __restrict__ g,
                                                const float* __restrict__ be,
                                                float* __restrict__ out) {
    __shared__ float lds[CH * 65];
    int bh = blockIdx.x;
    int b = bh >> 6, h = bh & 63;
    int tid = threadIdx.x;
    int wv = tid >> 6, lane = tid & 63;
    int c0 = lane * 4;
    bool act = lane < 48;
    int m1 = h >> 4, h0 = h & 15;
    int ubase = (b << 12) | (h0 << 8) | (m1 << 2);
    float gv[4], bv[4];
    #pragma unroll
    for (int j = 0; j < 4; ++j) { gv[j] = act ? g[c0 + j] : 0.f; bv[j] = act ? be[c0 + j] : 0.f; }
    for (int it = 0; it < 16; ++it) {
        int tok = it * 4 + wv;
        int u = ubase | ((tok & 15) << 4) | (tok >> 4);
        float v[4] = {0.f, 0.f, 0.f, 0.f};
        if (act) {
            uint2 ma = *reinterpret_cast<const uint2*>(Min + (size_t)u * CH + c0);
            uint2 ra = *reinterpret_cast<const uint2*>(Res + (size_t)u * CH + c0);
            const unsigned short* ms = reinterpret_cast<const unsigned short*>(&ma);
            const unsigned short* rs = reinterpret_cast<const unsigned short*>(&ra);
            #pragma unroll
            for (int j = 0; j < 4; ++j) v[j] = bf2f(ms[j]) + bf2f(rs[j]);
        }
        float s = v[0] + v[1] + v[2] + v[3];
        #pragma unroll
        for (int m = 1; m < 64; m <<= 1) s += __shfl_xor(s, m);
        float mean = s * (1.0f / 192.0f);
        float cv[4], ss = 0.f;
        #pragma unroll
        for (int j = 0; j < 4; ++j) { cv[j] = act ? (v[j] - mean) : 0.f; ss += cv[j] * cv[j]; }
        #pragma unroll
        for (int m = 1; m < 64; m <<= 1) ss += __shfl_xor(ss, m);
        float rcp = rsqrtf(ss * (1.0f / 192.0f) + 1e-5f);
        if (act) {
            #pragma unroll
            for (int j = 0; j < 4; ++j)
                lds[(c0 + j) * 65 + tok] = cv[j] * rcp * gv[j] + bv[j];
        }
    }
    __syncthreads();
    float* op = out + (size_t)b * CH * 4096 + (size_t)h * 64;
    #pragma unroll
    for (int it = 0; it < 48; ++it) {
        int idx = it * 256 + tid;
        int c = idx >> 6;
        int w = idx & 63;
        op[(size_t)c * 4096 + w] = lds[c * 65 + w];
    }
}

// ---------------------------------------------------------------------------
extern "C" void kernel_launch(void* const* d_in, const int* in_sizes, int n_in,
                              void* d_out, int out_size, void* d_ws, size_t ws_size,
                              hipStream_t stream) {
    const float* x   = (const float*)d_in[0];
    const float* wq  = (const float*)d_in[1];
    const float* wk  = (const float*)d_in[2];
    const float* wv  = (const float*)d_in[3];
    const float* wo  = (const float*)d_in[4];
    const float* w1  = (const float*)d_in[5];
    const float* b1  = (const float*)d_in[6];
    const float* w2  = (const float*)d_in[7];
    const float* b2  = (const float*)d_in[8];
    const float* g1  = (const float*)d_in[9];
    const float* be1 = (const float*)d_in[10];
    const float* g2  = (const float*)d_in[11];
    const float* be2 = (const float*)d_in[12];
    float* out = (float*)d_out;

    char* ws = (char*)d_ws;
    const size_t SZ = (size_t)NTOK * CH * sizeof(__hip_bfloat16);  // 50,331,648 B
    __hip_bfloat16* xt   = (__hip_bfloat16*)(ws);             // xt -> x1 (in-place LN1)
    __hip_bfloat16* qkv  = (__hip_bfloat16*)(ws + SZ);        // [N,576]; later h | m
    __hip_bfloat16* x1   = xt;
    __hip_bfloat16* hb   = qkv;                               // [65536,768] = 100.66MB
    __hip_bfloat16* mb   = (__hip_bfloat16*)(ws + SZ + (size_t)65536 * MLPD * 2);

    __hip_bfloat16* wqkvt = (__hip_bfloat16*)(ws + 4 * SZ);   // [576][192]
    __hip_bfloat16* wot   = wqkvt + 576 * 192;                // [192][192]
    __hip_bfloat16* w1t   = wot + 192 * 192;                  // [768][192]
    __hip_bfloat16* w2t   = w1t + 192 * 768;                  // [192][768]

    k_wprep<<<144, 256, 0, stream>>>(wq, wqkvt,             192, 192);
    k_wprep<<<144, 256, 0, stream>>>(wk, wqkvt + 192 * 192, 192, 192);
    k_wprep<<<144, 256, 0, stream>>>(wv, wqkvt + 384 * 192, 192, 192);
    k_wprep<<<144, 256, 0, stream>>>(wo, wot, 192, 192);
    k_wprep<<<576, 256, 0, stream>>>(w1, w1t, 192, 768);
    k_wprep<<<576, 256, 0, stream>>>(w2, w2t, 768, 192);

    k_tin<<<2048, 256, 0, stream>>>(x, xt);

    // qkv = xt @ [wq|wk|wv]
    k_mgemm<192, false, false><<<dim3(9, NTOK / 128), 256, 0, stream>>>(
        xt, wqkvt, nullptr, qkv, 192, 576);
    // attention (y -> v-slots of qkv)
    k_attn2<<<NTOK / 64, 256, 0, stream>>>(qkv);
    // x1 = LN(y @ wo + xt)  (in-place over xt)
    k_wogemm<<<NTOK / 128, 256, 0, stream>>>(qkv + 384, wot, xt, g1, be1, x1);

    // MLP in 2 chunks of 65536 rows (h reuses qkv area)
    const int CHUNK = 65536;
    for (int c = 0; c < 2; ++c) {
        const __hip_bfloat16* x1c = x1 + (size_t)c * CHUNK * CH;
        __hip_bfloat16* mc = mb + (size_t)c * CHUNK * CH;
        k_mgemm<192, true,  true ><<<dim3(12, CHUNK / 128), 256, 0, stream>>>(
            x1c, w1t, b1, hb, 192, MLPD);
        k_mgemm<MLPD, false, true ><<<dim3(3, CHUNK / 128), 256, 0, stream>>>(
            hb, w2t, b2, mc, MLPD, 192);
    }
    k_ln_out<<<2048, 256, 0, stream>>>(mb, x1, g2, be2, out);
}